// Round 1
// baseline (183.387 us; speedup 1.0000x reference)
//
#include <hip/hip_runtime.h>
#include <math.h>

// Problem constants
static constexpr int N    = 8192;
static constexpr int DIM  = 512;
static constexpr int DK   = 128;
static constexpr int DV   = 128;
static constexpr float SLOPE = 0.01f;

// Scan partitioning
static constexpr int NCH  = 128;   // chunks
static constexpr int CHSZ = 64;    // elems per chunk (NCH*CHSZ == N)
static constexpr int NCOL = 258;   // 128 (e1*v) + 128 (e2*v) + z1 + z2

// ---------------------------------------------------------------------------
// K1: u_src = W^T @ a[:DK], u_dst = W^T @ a[DK:], c = b . a  (double precision)
// ---------------------------------------------------------------------------
__global__ void k_prep(const float* __restrict__ W, const float* __restrict__ b,
                       const float* __restrict__ a,
                       double* __restrict__ u_src, double* __restrict__ u_dst,
                       double* __restrict__ cvals) {
    int dim = threadIdx.x;  // 512 threads
    double us = 0.0, ud = 0.0;
    for (int k = 0; k < DK; ++k) {
        double w = (double)W[(size_t)k * DIM + dim];
        us += w * (double)a[k];
        ud += w * (double)a[DK + k];
    }
    u_src[dim] = us;
    u_dst[dim] = ud;
    __shared__ double sb0[DK], sb1[DK];
    if (dim < DK) {
        sb0[dim] = (double)b[dim] * (double)a[dim];
        sb1[dim] = (double)b[dim] * (double)a[DK + dim];
    }
    __syncthreads();
    if (dim == 0) {
        double c0 = 0.0, c1 = 0.0;
        for (int k = 0; k < DK; ++k) { c0 += sb0[k]; c1 += sb1[k]; }
        cvals[0] = c0; cvals[1] = c1;
    }
}

// ---------------------------------------------------------------------------
// K2: s_src[i] = x[i].u_src + c0 ; s_dst[i] = x[i].u_dst + c1
// one wave per row, 4 rows per block
// ---------------------------------------------------------------------------
__global__ void k_s(const float* __restrict__ x,
                    const double* __restrict__ u_src, const double* __restrict__ u_dst,
                    const double* __restrict__ cvals,
                    float* __restrict__ s_src, float* __restrict__ s_dst) {
    int wave = threadIdx.x >> 6;
    int lane = threadIdx.x & 63;
    int row  = blockIdx.x * 4 + wave;
    const float* xr = x + (size_t)row * DIM;
    float xv[8];
    *reinterpret_cast<float4*>(&xv[0]) = *reinterpret_cast<const float4*>(xr + lane * 8);
    *reinterpret_cast<float4*>(&xv[4]) = *reinterpret_cast<const float4*>(xr + lane * 8 + 4);
    double as = 0.0, ad = 0.0;
#pragma unroll
    for (int t = 0; t < 8; ++t) {
        int d = lane * 8 + t;
        double xd = (double)xv[t];
        as += xd * u_src[d];
        ad += xd * u_dst[d];
    }
#pragma unroll
    for (int off = 32; off > 0; off >>= 1) {
        as += __shfl_down(as, off);
        ad += __shfl_down(ad, off);
    }
    if (lane == 0) {
        s_src[row] = (float)(as + cvals[0]);
        s_dst[row] = (float)(ad + cvals[1]);
    }
}

// ---------------------------------------------------------------------------
// K3: v = x @ Wv^T + bv   [N, DV] fp32, tiled. BM=64 rows, BN=64 cols, BK=64.
// grid (N/64, DV/64) = (128, 2); 256 threads; each thread 4 rows x 4 cols.
// ---------------------------------------------------------------------------
static constexpr int BM = 64;
static constexpr int BN = 64;
static constexpr int BK = 64;
static constexpr int LDP = BK + 4;  // 68 floats; row stride 272 B (16B aligned)

__global__ __launch_bounds__(256) void k_v(const float* __restrict__ x,
                                           const float* __restrict__ Wv,
                                           const float* __restrict__ bv,
                                           float* __restrict__ v) {
    __shared__ __align__(16) float xs[BM][LDP];
    __shared__ __align__(16) float wvs[BN][LDP];
    int tid  = threadIdx.x;
    int row0 = blockIdx.x * BM;
    int col0 = blockIdx.y * BN;
    int tx = tid & 15, ty = tid >> 4;  // 16 x 16

    float acc[4][4];
#pragma unroll
    for (int r = 0; r < 4; ++r)
#pragma unroll
        for (int c = 0; c < 4; ++c) acc[r][c] = 0.0f;

    for (int kc = 0; kc < DIM; kc += BK) {
        __syncthreads();
        // load x tile: 64x64 = 1024 float4, 4 per thread
#pragma unroll
        for (int i = 0; i < 4; ++i) {
            int f = tid + i * 256;
            int r = f >> 4, c4 = f & 15;
            float4 q = *reinterpret_cast<const float4*>(x + (size_t)(row0 + r) * DIM + kc + c4 * 4);
            *reinterpret_cast<float4*>(&xs[r][c4 * 4]) = q;
        }
        // load Wv tile: 64x64 = 1024 float4, 4 per thread
#pragma unroll
        for (int i = 0; i < 4; ++i) {
            int f = tid + i * 256;
            int r = f >> 4, c4 = f & 15;
            float4 q = *reinterpret_cast<const float4*>(Wv + (size_t)(col0 + r) * DIM + kc + c4 * 4);
            *reinterpret_cast<float4*>(&wvs[r][c4 * 4]) = q;
        }
        __syncthreads();

        for (int k4 = 0; k4 < BK; k4 += 4) {
            float4 ar[4], br[4];
#pragma unroll
            for (int r = 0; r < 4; ++r)
                ar[r] = *reinterpret_cast<const float4*>(&xs[ty * 4 + r][k4]);
#pragma unroll
            for (int c = 0; c < 4; ++c)
                br[c] = *reinterpret_cast<const float4*>(&wvs[tx + 16 * c][k4]);
#pragma unroll
            for (int r = 0; r < 4; ++r)
#pragma unroll
                for (int c = 0; c < 4; ++c) {
                    acc[r][c] += ar[r].x * br[c].x + ar[r].y * br[c].y +
                                 ar[r].z * br[c].z + ar[r].w * br[c].w;
                }
        }
    }
#pragma unroll
    for (int r = 0; r < 4; ++r) {
        int row = row0 + ty * 4 + r;
#pragma unroll
        for (int c = 0; c < 4; ++c) {
            int col = col0 + tx + 16 * c;
            v[(size_t)row * DV + col] = acc[r][c] + bv[col];
        }
    }
}

// ---------------------------------------------------------------------------
// K4: rank each s_dst value (count of strictly-smaller, tie-break by index).
// grid (32 j-groups, 8 compare-chunks); partial counts via atomicAdd.
// ---------------------------------------------------------------------------
__global__ void k_count(const float* __restrict__ s_dst, int* __restrict__ rank) {
    __shared__ __align__(16) float sd[1024];
    int jb = blockIdx.x, cb = blockIdx.y;
    int tid = threadIdx.x;  // 256
    for (int t = tid; t < 1024; t += 256) sd[t] = s_dst[cb * 1024 + t];
    __syncthreads();
    int j = jb * 256 + tid;
    float dj = s_dst[j];
    int base = cb * 1024;
    int cnt = 0;
    const float4* sdv = reinterpret_cast<const float4*>(sd);
    for (int c = 0; c < 256; ++c) {
        float4 q = sdv[c];
        int i0 = base + c * 4;
        cnt += (q.x < dj || (q.x == dj && (i0 + 0) < j));
        cnt += (q.y < dj || (q.y == dj && (i0 + 1) < j));
        cnt += (q.z < dj || (q.z == dj && (i0 + 2) < j));
        cnt += (q.w < dj || (q.w == dj && (i0 + 3) < j));
    }
    atomicAdd(&rank[j], cnt);
}

__global__ void k_scatter(const float* __restrict__ s_dst, const int* __restrict__ rank,
                          float* __restrict__ d_sorted, int* __restrict__ perm) {
    int j = blockIdx.x * 256 + threadIdx.x;
    int r = rank[j];
    d_sorted[r] = s_dst[j];
    perm[r] = j;
}

// ---------------------------------------------------------------------------
// K5a: per-chunk totals of [e1*v | e2*v | z1 | z2] over sorted order (double).
// block = chunk (256 threads: t<128 -> e1*v col t ; t>=128 -> e2*v col t-128)
// ---------------------------------------------------------------------------
__global__ void k_chunk_tot(const float* __restrict__ d_sorted, const int* __restrict__ perm,
                            const float* __restrict__ v, double* __restrict__ chunk_tot) {
    int ch = blockIdx.x, tid = threadIdx.x;
    __shared__ float e1s[CHSZ], e2s[CHSZ];
    __shared__ int pk[CHSZ];
    float dmax = d_sorted[N - 1];
    if (tid < CHSZ) {
        float d = d_sorted[ch * CHSZ + tid];
        e1s[tid] = expf(d - dmax);
        e2s[tid] = expf(SLOPE * d);
        pk[tid]  = perm[ch * CHSZ + tid];
    }
    __syncthreads();
    int col = tid & 127;
    bool isP2 = tid >= 128;
    double acc = 0.0;
    for (int k = 0; k < CHSZ; ++k) {
        float e = isP2 ? e2s[k] : e1s[k];
        acc += (double)e * (double)v[(size_t)pk[k] * DV + col];
    }
    chunk_tot[(size_t)ch * NCOL + tid] = acc;
    if (tid == 0) {
        double z = 0.0;
        for (int k = 0; k < CHSZ; ++k) z += (double)e1s[k];
        chunk_tot[(size_t)ch * NCOL + 256] = z;
    }
    if (tid == 1) {
        double z = 0.0;
        for (int k = 0; k < CHSZ; ++k) z += (double)e2s[k];
        chunk_tot[(size_t)ch * NCOL + 257] = z;
    }
}

// K5b: exclusive scan of chunk totals across chunks (single block, 320 thr)
__global__ void k_chunk_off(const double* __restrict__ chunk_tot, double* __restrict__ chunk_off,
                            double* __restrict__ totals) {
    int col = threadIdx.x;
    if (col >= NCOL) return;
    double off = 0.0;
    for (int ch = 0; ch < NCH; ++ch) {
        chunk_off[(size_t)ch * NCOL + col] = off;
        off += chunk_tot[(size_t)ch * NCOL + col];
    }
    totals[col] = off;
}

// K5c: within-chunk exclusive scans -> P1 (e1*v prefix), P2 (e2*v prefix),
//      pz1/pz2 scalar prefixes (double).
__global__ void k_scan(const float* __restrict__ d_sorted, const int* __restrict__ perm,
                       const float* __restrict__ v, const double* __restrict__ chunk_off,
                       float* __restrict__ P1, float* __restrict__ P2,
                       double* __restrict__ pz1, double* __restrict__ pz2) {
    int ch = blockIdx.x, tid = threadIdx.x;
    __shared__ float e1s[CHSZ], e2s[CHSZ];
    __shared__ int pk[CHSZ];
    float dmax = d_sorted[N - 1];
    if (tid < CHSZ) {
        float d = d_sorted[ch * CHSZ + tid];
        e1s[tid] = expf(d - dmax);
        e2s[tid] = expf(SLOPE * d);
        pk[tid]  = perm[ch * CHSZ + tid];
    }
    __syncthreads();
    int col = tid & 127;
    bool isP2 = tid >= 128;
    float* P = isP2 ? P2 : P1;
    double acc = chunk_off[(size_t)ch * NCOL + tid];
    for (int k = 0; k < CHSZ; ++k) {
        int kg = ch * CHSZ + k;
        P[(size_t)kg * DV + col] = (float)acc;
        float e = isP2 ? e2s[k] : e1s[k];
        acc += (double)e * (double)v[(size_t)pk[k] * DV + col];
    }
    if (tid == 0) {
        double z = chunk_off[(size_t)ch * NCOL + 256];
        for (int k = 0; k < CHSZ; ++k) { pz1[ch * CHSZ + k] = z; z += (double)e1s[k]; }
    }
    if (tid == 1) {
        double z = chunk_off[(size_t)ch * NCOL + 257];
        for (int k = 0; k < CHSZ; ++k) { pz2[ch * CHSZ + k] = z; z += (double)e2s[k]; }
    }
}

// ---------------------------------------------------------------------------
// K6: finalize. out[i,:] = (a*suffix1(ki) + b*prefix2(ki)) / (a*sz1 + b*sz2)
// one block (128 threads) per row.
// ---------------------------------------------------------------------------
__global__ void k_final(const float* __restrict__ s_src, const float* __restrict__ d_sorted,
                        const float* __restrict__ P1, const float* __restrict__ P2,
                        const double* __restrict__ pz1, const double* __restrict__ pz2,
                        const double* __restrict__ totals, float* __restrict__ out) {
    int row = blockIdx.x;
    int dv  = threadIdx.x;  // 128
    float si = s_src[row];
    float dmax = d_sorted[N - 1];
    float t = si + dmax;
    float m = t > 0.0f ? t : SLOPE * t;         // true row max after leaky_relu
    float thr = -si;
    int lo = 0, hi = N;
    while (lo < hi) {                            // ki = #{ d_sorted[k] <= -si }
        int mid = (lo + hi) >> 1;
        if (d_sorted[mid] <= thr) lo = mid + 1; else hi = mid;
    }
    int ki = lo;
    float alpha = expf(t - m);                   // exp(si + dmax - m); ==1 when t>0
    float beta  = expf(SLOPE * si - m);
    double T1 = totals[dv];
    double T2 = totals[128 + dv];
    double z1T = totals[256], z2T = totals[257];
    double suf1, sufz1, pre2, prez2;
    if (ki < N) {
        suf1  = T1 - (double)P1[(size_t)ki * DV + dv];
        sufz1 = z1T - pz1[ki];
        pre2  = (double)P2[(size_t)ki * DV + dv];
        prez2 = pz2[ki];
    } else {
        suf1 = 0.0; sufz1 = 0.0; pre2 = T2; prez2 = z2T;
    }
    double num = (double)alpha * suf1  + (double)beta * pre2;
    double den = (double)alpha * sufz1 + (double)beta * prez2;
    out[(size_t)row * DV + dv] = (float)(num / den);
}

// ---------------------------------------------------------------------------
extern "C" void kernel_launch(void* const* d_in, const int* in_sizes, int n_in,
                              void* d_out, int out_size, void* d_ws, size_t ws_size,
                              hipStream_t stream) {
    const float* x  = (const float*)d_in[0];
    const float* W  = (const float*)d_in[1];
    const float* b  = (const float*)d_in[2];
    const float* Wv = (const float*)d_in[3];
    const float* bv = (const float*)d_in[4];
    const float* a  = (const float*)d_in[5];
    float* out = (float*)d_out;

    // Carve workspace (~9.2 MB total)
    char* base = (char*)d_ws;
    size_t off = 0;
    auto carve = [&](size_t bytes) -> void* {
        void* p = base + off;
        off = (off + bytes + 255) & ~(size_t)255;
        return p;
    };
    double* u_src     = (double*)carve(DIM * sizeof(double));
    double* u_dst     = (double*)carve(DIM * sizeof(double));
    double* cvals     = (double*)carve(2 * sizeof(double));
    float*  s_src     = (float*)carve(N * sizeof(float));
    float*  s_dst     = (float*)carve(N * sizeof(float));
    float*  d_sorted  = (float*)carve(N * sizeof(float));
    int*    perm      = (int*)carve(N * sizeof(int));
    int*    rank      = (int*)carve(N * sizeof(int));
    double* pz1       = (double*)carve(N * sizeof(double));
    double* pz2       = (double*)carve(N * sizeof(double));
    double* chunk_tot = (double*)carve((size_t)NCH * NCOL * sizeof(double));
    double* chunk_off = (double*)carve((size_t)NCH * NCOL * sizeof(double));
    double* totals    = (double*)carve(NCOL * sizeof(double));
    float*  P1        = (float*)carve((size_t)N * DV * sizeof(float));
    float*  P2        = (float*)carve((size_t)N * DV * sizeof(float));
    float*  v         = out;  // use d_out as the v buffer (dead before k_final writes)

    hipMemsetAsync(rank, 0, N * sizeof(int), stream);
    k_prep<<<1, 512, 0, stream>>>(W, b, a, u_src, u_dst, cvals);
    k_s<<<N / 4, 256, 0, stream>>>(x, u_src, u_dst, cvals, s_src, s_dst);
    k_v<<<dim3(N / BM, DV / BN), 256, 0, stream>>>(x, Wv, bv, v);
    k_count<<<dim3(32, 8), 256, 0, stream>>>(s_dst, rank);
    k_scatter<<<N / 256, 256, 0, stream>>>(s_dst, rank, d_sorted, perm);
    k_chunk_tot<<<NCH, 256, 0, stream>>>(d_sorted, perm, v, chunk_tot);
    k_chunk_off<<<1, 320, 0, stream>>>(chunk_tot, chunk_off, totals);
    k_scan<<<NCH, 256, 0, stream>>>(d_sorted, perm, v, chunk_off, P1, P2, pz1, pz2);
    k_final<<<N, 128, 0, stream>>>(s_src, d_sorted, P1, P2, pz1, pz2, totals, out);
}